// Round 1
// baseline (322.415 us; speedup 1.0000x reference)
//
#include <hip/hip_runtime.h>

#define L_SEQ 4096
#define DM 1024
#define NH 16
#define DK 64

typedef short s16x8 __attribute__((ext_vector_type(8)));
typedef float f32x4 __attribute__((ext_vector_type(4)));
typedef unsigned short u16t;
typedef unsigned int u32t;

typedef __attribute__((address_space(1))) unsigned int as1_u32;
typedef __attribute__((address_space(3))) unsigned int as3_u32;

#define GLOAD_LDS16(gsrc, ldst) \
  __builtin_amdgcn_global_load_lds((as1_u32*)(gsrc), (as3_u32*)(ldst), 16, 0, 0)

__device__ __forceinline__ u16t f2bf(float f) {
  union { float f; unsigned u; } v; v.f = f;
  unsigned u = v.u;
  u += 0x7fffu + ((u >> 16) & 1u);   // RNE
  return (u16t)(u >> 16);
}

// ---------------------------------------------------------------------------
// f32 -> bf16 conversion, 8 elems/thread
// ---------------------------------------------------------------------------
__global__ __launch_bounds__(256) void cvt_f32_bf16(const float* __restrict__ in,
                                                    u16t* __restrict__ out, int n) {
  int i = blockIdx.x * blockDim.x + threadIdx.x;
  int base = i * 8;
  if (base >= n) return;
  float4 x = *(const float4*)(in + base);
  float4 y = *(const float4*)(in + base + 4);
  uint4 o;
  o.x = (u32t)f2bf(x.x) | ((u32t)f2bf(x.y) << 16);
  o.y = (u32t)f2bf(x.z) | ((u32t)f2bf(x.w) << 16);
  o.z = (u32t)f2bf(y.x) | ((u32t)f2bf(y.y) << 16);
  o.w = (u32t)f2bf(y.z) | ((u32t)f2bf(y.w) << 16);
  *(uint4*)(out + base) = o;
}

// ---------------------------------------------------------------------------
// C[i][j] = sum_k A[i][k] * B[j][k] + bias[j or i]
// A: M x K bf16 row-major, B: N x K bf16 row-major. 128x128 tile, BK=32.
// LDS: linear dest for global_load_lds, source pre-swizzled, reads swizzled
// (rule #21). Swizzle: 16B-slot col c' = c ^ ((row>>1)&3) -> 2-way (free).
// ---------------------------------------------------------------------------
template <bool BF16_OUT, bool ROW_BIAS>
__global__ __launch_bounds__(256)
void gemm_bt(const u16t* __restrict__ A, const u16t* __restrict__ B,
             const float* __restrict__ bias, void* __restrict__ Cv,
             int M, int N, int K) {
  __shared__ unsigned char lds[2][2][8192];
  const int tid = threadIdx.x;
  const int lane = tid & 63;
  const int wv = tid >> 6;
  const int wr = wv >> 1, wc = wv & 1;
  const int l15 = lane & 15, l4 = lane >> 4;
  const int bc = blockIdx.x, br = blockIdx.y;

  // staging: slot index = tid (linear LDS dest), inverse-swizzled global source
  const int r_st = tid >> 2;                          // row 0..63 per issue
  const int c_st = (tid & 3) ^ ((r_st >> 1) & 3);     // source k-chunk
  const u16t* a0 = A + (size_t)(br * 128 + r_st) * K + c_st * 8;
  const u16t* a1 = a0 + (size_t)64 * K;
  const u16t* b0 = B + (size_t)(bc * 128 + r_st) * K + c_st * 8;
  const u16t* b1 = b0 + (size_t)64 * K;
  const int woff = wv * 1024;

  f32x4 acc[4][4] = {};

  auto stage = [&](int buf, int k0) {
    GLOAD_LDS16(a0 + k0, &lds[buf][0][woff]);
    GLOAD_LDS16(a1 + k0, &lds[buf][0][4096 + woff]);
    GLOAD_LDS16(b0 + k0, &lds[buf][1][woff]);
    GLOAD_LDS16(b1 + k0, &lds[buf][1][4096 + woff]);
  };

  const int nt = K >> 5;
  stage(0, 0);
  int buf = 0;
  for (int t = 0; t < nt; ++t) {
    __syncthreads();                       // drains vmcnt -> staged tile ready
    if (t + 1 < nt) stage(buf ^ 1, (t + 1) * 32);
    s16x8 af[4], bfr[4];
    #pragma unroll
    for (int m = 0; m < 4; ++m) {
      int r = wr * 64 + m * 16 + l15;
      int sl = l4 ^ ((r >> 1) & 3);
      af[m] = *(const s16x8*)&lds[buf][0][r * 64 + (sl << 4)];
    }
    #pragma unroll
    for (int n = 0; n < 4; ++n) {
      int r = wc * 64 + n * 16 + l15;
      int sl = l4 ^ ((r >> 1) & 3);
      bfr[n] = *(const s16x8*)&lds[buf][1][r * 64 + (sl << 4)];
    }
    #pragma unroll
    for (int m = 0; m < 4; ++m)
      #pragma unroll
      for (int n = 0; n < 4; ++n)
        acc[m][n] = __builtin_amdgcn_mfma_f32_16x16x32_bf16(af[m], bfr[n], acc[m][n], 0, 0, 0);
    buf ^= 1;
  }

  #pragma unroll
  for (int m = 0; m < 4; ++m) {
    #pragma unroll
    for (int n = 0; n < 4; ++n) {
      #pragma unroll
      for (int i = 0; i < 4; ++i) {
        int row = br * 128 + wr * 64 + m * 16 + l4 * 4 + i;
        int col = bc * 128 + wc * 64 + n * 16 + l15;
        float v = acc[m][n][i] + (ROW_BIAS ? bias[row] : bias[col]);
        if (BF16_OUT) ((u16t*)Cv)[(size_t)row * N + col] = f2bf(v);
        else          ((float*)Cv)[(size_t)row * N + col] = v;
      }
    }
  }
}

// ---------------------------------------------------------------------------
// Flash attention. Qp,Kp: [L][1024] bf16 (head h = cols h*64..h*64+63).
// VpT: [1024][L] bf16 (row j = h*64+d). AO: [L][1024] bf16.
// Block: 4 waves, 64 q-rows (16/wave), KV tiles of 64. scale = 1/8.
// LDS rows are 128B -> swizzle 16B slot ^= (row&7) on both write and read.
// ---------------------------------------------------------------------------
__global__ __launch_bounds__(256)
void attn_fused(const u16t* __restrict__ Qp, const u16t* __restrict__ Kp,
                const u16t* __restrict__ VpT, u16t* __restrict__ AO) {
  __shared__ unsigned char sK[8192];      // [64 kj][64 d]
  __shared__ unsigned char sV[8192];      // [64 d][64 kj] (pre-transposed global)
  __shared__ unsigned char sP[4][2048];   // per-wave [16 q][64 kj]

  const int tid = threadIdx.x;
  const int lane = tid & 63;
  const int w = tid >> 6;
  const int l15 = lane & 15;
  const int l4 = lane >> 4;
  const int h = blockIdx.y;
  const int qbase = blockIdx.x * 64;

  // Q fragments: lane holds Q[row = qbase+w*16+l15][d = ch*32 + l4*8 + 0..7]
  s16x8 qf[2];
  {
    const u16t* qsrc = Qp + (size_t)(qbase + w * 16 + l15) * DM + h * DK + l4 * 8;
    qf[0] = *(const s16x8*)(qsrc);
    qf[1] = *(const s16x8*)(qsrc + 32);
  }

  f32x4 acc[4] = {};
  float mrow[4] = {-1e30f, -1e30f, -1e30f, -1e30f};
  float lrow[4] = {0.f, 0.f, 0.f, 0.f};

  for (int kv = 0; kv < L_SEQ; kv += 64) {
    __syncthreads();                      // all waves done reading prev tile
    #pragma unroll
    for (int s = 0; s < 2; ++s) {
      int slot = tid + s * 256;           // 512 x 16B slots per tile
      int r = slot >> 3, c = slot & 7;
      uint4 dk = *(const uint4*)(Kp + (size_t)(kv + r) * DM + h * DK + c * 8);
      *(uint4*)(sK + r * 128 + ((c ^ (r & 7)) << 4)) = dk;
      uint4 dv = *(const uint4*)(VpT + (size_t)(h * DK + r) * L_SEQ + kv + c * 8);
      *(uint4*)(sV + r * 128 + ((c ^ (r & 7)) << 4)) = dv;
    }
    __syncthreads();

    // S = Q K^T : 16 q x 64 kj per wave
    f32x4 sc[4];
    #pragma unroll
    for (int c = 0; c < 4; ++c) {
      f32x4 z = {};
      #pragma unroll
      for (int ch = 0; ch < 2; ++ch) {
        int r = c * 16 + l15;
        int sl = (ch * 4 + l4) ^ (r & 7);
        s16x8 kf = *(const s16x8*)(sK + r * 128 + (sl << 4));
        z = __builtin_amdgcn_mfma_f32_16x16x32_bf16(qf[ch], kf, z, 0, 0, 0);
      }
      sc[c] = z;
    }

    // online softmax (rows l4*4+i, 16 cols/lane-group)
    float tmax[4];
    #pragma unroll
    for (int i = 0; i < 4; ++i) {
      float v = fmaxf(fmaxf(sc[0][i], sc[1][i]), fmaxf(sc[2][i], sc[3][i])) * 0.125f;
      v = fmaxf(v, __shfl_xor(v, 1));
      v = fmaxf(v, __shfl_xor(v, 2));
      v = fmaxf(v, __shfl_xor(v, 4));
      v = fmaxf(v, __shfl_xor(v, 8));
      tmax[i] = v;
    }
    float alpha[4];
    #pragma unroll
    for (int i = 0; i < 4; ++i) {
      float mn = fmaxf(mrow[i], tmax[i]);
      alpha[i] = __expf(mrow[i] - mn);
      mrow[i] = mn;
    }
    float rs[4] = {0.f, 0.f, 0.f, 0.f};
    #pragma unroll
    for (int c = 0; c < 4; ++c) {
      #pragma unroll
      for (int i = 0; i < 4; ++i) {
        float p = __expf(sc[c][i] * 0.125f - mrow[i]);
        rs[i] += p;
        int row = l4 * 4 + i;
        int col = c * 16 + l15;
        int sl = (col >> 3) ^ (row & 7);
        *(u16t*)(sP[w] + row * 128 + (sl << 4) + (col & 7) * 2) = f2bf(p);
      }
    }
    #pragma unroll
    for (int i = 0; i < 4; ++i) {
      float v = rs[i];
      v += __shfl_xor(v, 1);
      v += __shfl_xor(v, 2);
      v += __shfl_xor(v, 4);
      v += __shfl_xor(v, 8);
      lrow[i] = lrow[i] * alpha[i] + v;
      acc[0][i] *= alpha[i];
      acc[1][i] *= alpha[i];
      acc[2][i] *= alpha[i];
      acc[3][i] *= alpha[i];
    }
    __asm__ volatile("s_waitcnt lgkmcnt(0)" ::: "memory");  // P writes visible

    // P A-frags: lane holds P[l15][ch*32 + l4*8 + 0..7]
    s16x8 pa[2];
    #pragma unroll
    for (int ch = 0; ch < 2; ++ch) {
      int sl = (ch * 4 + l4) ^ (l15 & 7);
      pa[ch] = *(const s16x8*)(sP[w] + l15 * 128 + (sl << 4));
    }
    // PV: acc[t] over d-tiles, B-frag from V^T: lane holds V[kj][dtile*16+l15]
    #pragma unroll
    for (int t = 0; t < 4; ++t) {
      #pragma unroll
      for (int ch = 0; ch < 2; ++ch) {
        int r = t * 16 + l15;
        int sl = (ch * 4 + l4) ^ (r & 7);
        s16x8 vf = *(const s16x8*)(sV + r * 128 + (sl << 4));
        acc[t] = __builtin_amdgcn_mfma_f32_16x16x32_bf16(pa[ch], vf, acc[t], 0, 0, 0);
      }
    }
  }

  #pragma unroll
  for (int t = 0; t < 4; ++t) {
    #pragma unroll
    for (int i = 0; i < 4; ++i) {
      int row = qbase + w * 16 + l4 * 4 + i;
      int col = h * DK + t * 16 + l15;
      AO[(size_t)row * DM + col] = f2bf(acc[t][i] / lrow[i]);
    }
  }
}

// ---------------------------------------------------------------------------
extern "C" void kernel_launch(void* const* d_in, const int* in_sizes, int n_in,
                              void* d_out, int out_size, void* d_ws, size_t ws_size,
                              hipStream_t stream) {
  const float* query = (const float*)d_in[0];
  const float* key_  = (const float*)d_in[1];
  const float* value = (const float*)d_in[2];
  const float* Wq = (const float*)d_in[3];
  const float* Wk = (const float*)d_in[4];
  const float* Wv = (const float*)d_in[5];
  const float* Wo = (const float*)d_in[6];
  const float* bq = (const float*)d_in[7];
  const float* bk = (const float*)d_in[8];
  const float* bv = (const float*)d_in[9];
  const float* bo = (const float*)d_in[10];

  char* ws = (char*)d_ws;
  const size_t MB = 1u << 20;
  u16t* qb  = (u16t*)(ws + 0 * MB);   // query bf16           [4096][1024]
  u16t* kb  = (u16t*)(ws + 8 * MB);   // key bf16
  u16t* vb  = (u16t*)(ws + 16 * MB);  // value bf16
  u16t* wqb = (u16t*)(ws + 24 * MB);  // Wq bf16              [1024][1024]
  u16t* wkb = (u16t*)(ws + 26 * MB);
  u16t* wvb = (u16t*)(ws + 28 * MB);
  u16t* wob = (u16t*)(ws + 30 * MB);
  u16t* Qp  = (u16t*)(ws + 32 * MB);  // Q projected bf16     [4096][1024]
  u16t* Kp  = (u16t*)(ws + 40 * MB);  // K projected bf16
  u16t* VpT = (u16t*)(ws + 48 * MB);  // V projected, transposed [1024][4096]
  u16t* AO  = (u16t*)(ws + 56 * MB);  // attention out bf16   [4096][1024]

  const int nQKV = L_SEQ * DM;  // 4194304
  const int nW = DM * DM;       // 1048576
  dim3 blk(256);

  cvt_f32_bf16<<<dim3(nQKV / 2048), blk, 0, stream>>>(query, qb, nQKV);
  cvt_f32_bf16<<<dim3(nQKV / 2048), blk, 0, stream>>>(key_,  kb, nQKV);
  cvt_f32_bf16<<<dim3(nQKV / 2048), blk, 0, stream>>>(value, vb, nQKV);
  cvt_f32_bf16<<<dim3(nW / 2048), blk, 0, stream>>>(Wq, wqb, nW);
  cvt_f32_bf16<<<dim3(nW / 2048), blk, 0, stream>>>(Wk, wkb, nW);
  cvt_f32_bf16<<<dim3(nW / 2048), blk, 0, stream>>>(Wv, wvb, nW);
  cvt_f32_bf16<<<dim3(nW / 2048), blk, 0, stream>>>(Wo, wob, nW);

  // Q = query @ Wq^T + bq ; K likewise
  gemm_bt<true, false><<<dim3(DM / 128, L_SEQ / 128), blk, 0, stream>>>(
      qb, wqb, bq, Qp, L_SEQ, DM, DM);
  gemm_bt<true, false><<<dim3(DM / 128, L_SEQ / 128), blk, 0, stream>>>(
      kb, wkb, bk, Kp, L_SEQ, DM, DM);
  // V^T directly: VpT[j][i] = Wv[j]·value[i] + bv[j]  (row-bias)
  gemm_bt<true, true><<<dim3(L_SEQ / 128, DM / 128), blk, 0, stream>>>(
      wvb, vb, bv, VpT, DM, L_SEQ, DM);

  attn_fused<<<dim3(L_SEQ / 64, NH), blk, 0, stream>>>(Qp, Kp, VpT, AO);

  // out = AO @ Wo^T + bo (f32 out)
  gemm_bt<false, false><<<dim3(DM / 128, L_SEQ / 128), blk, 0, stream>>>(
      AO, wob, bo, d_out, L_SEQ, DM, DM);
}

// Round 2
// 199.988 us; speedup vs baseline: 1.6122x; 1.6122x over previous
//
#include <hip/hip_runtime.h>

#define L_SEQ 4096
#define DM 1024
#define NH 16
#define DK 64

typedef short s16x8 __attribute__((ext_vector_type(8)));
typedef float f32x4 __attribute__((ext_vector_type(4)));
typedef float f32x16 __attribute__((ext_vector_type(16)));
typedef unsigned u32x2 __attribute__((ext_vector_type(2)));
typedef unsigned short u16t;
typedef unsigned int u32t;

typedef __attribute__((address_space(1))) unsigned int as1_u32;
typedef __attribute__((address_space(3))) unsigned int as3_u32;

#define GLOAD_LDS16(gsrc, ldst) \
  __builtin_amdgcn_global_load_lds((as1_u32*)(gsrc), (as3_u32*)(ldst), 16, 0, 0)

__device__ __forceinline__ u16t f2bf(float f) {
  union { float f; unsigned u; } v; v.f = f;
  unsigned u = v.u;
  u += 0x7fffu + ((u >> 16) & 1u);   // RNE
  return (u16t)(u >> 16);
}

// ---------------------------------------------------------------------------
// f32 -> bf16 conversion, 8 elems/thread
// ---------------------------------------------------------------------------
__global__ __launch_bounds__(256) void cvt_f32_bf16(const float* __restrict__ in,
                                                    u16t* __restrict__ out, int n) {
  int i = blockIdx.x * blockDim.x + threadIdx.x;
  int base = i * 8;
  if (base >= n) return;
  float4 x = *(const float4*)(in + base);
  float4 y = *(const float4*)(in + base + 4);
  uint4 o;
  o.x = (u32t)f2bf(x.x) | ((u32t)f2bf(x.y) << 16);
  o.y = (u32t)f2bf(x.z) | ((u32t)f2bf(x.w) << 16);
  o.z = (u32t)f2bf(y.x) | ((u32t)f2bf(y.y) << 16);
  o.w = (u32t)f2bf(y.z) | ((u32t)f2bf(y.w) << 16);
  *(uint4*)(out + base) = o;
}

// ---------------------------------------------------------------------------
// C[i][j] = sum_k A[i][k] * B[j][k] + bias[j or i]   (unchanged from R1)
// ---------------------------------------------------------------------------
template <bool BF16_OUT, bool ROW_BIAS>
__global__ __launch_bounds__(256)
void gemm_bt(const u16t* __restrict__ A, const u16t* __restrict__ B,
             const float* __restrict__ bias, void* __restrict__ Cv,
             int M, int N, int K) {
  __shared__ unsigned char lds[2][2][8192];
  const int tid = threadIdx.x;
  const int lane = tid & 63;
  const int wv = tid >> 6;
  const int wr = wv >> 1, wc = wv & 1;
  const int l15 = lane & 15, l4 = lane >> 4;
  const int bc = blockIdx.x, br = blockIdx.y;

  const int r_st = tid >> 2;
  const int c_st = (tid & 3) ^ ((r_st >> 1) & 3);
  const u16t* a0 = A + (size_t)(br * 128 + r_st) * K + c_st * 8;
  const u16t* a1 = a0 + (size_t)64 * K;
  const u16t* b0 = B + (size_t)(bc * 128 + r_st) * K + c_st * 8;
  const u16t* b1 = b0 + (size_t)64 * K;
  const int woff = wv * 1024;

  f32x4 acc[4][4] = {};

  auto stage = [&](int buf, int k0) {
    GLOAD_LDS16(a0 + k0, &lds[buf][0][woff]);
    GLOAD_LDS16(a1 + k0, &lds[buf][0][4096 + woff]);
    GLOAD_LDS16(b0 + k0, &lds[buf][1][woff]);
    GLOAD_LDS16(b1 + k0, &lds[buf][1][4096 + woff]);
  };

  const int nt = K >> 5;
  stage(0, 0);
  int buf = 0;
  for (int t = 0; t < nt; ++t) {
    __syncthreads();
    if (t + 1 < nt) stage(buf ^ 1, (t + 1) * 32);
    s16x8 af[4], bfr[4];
    #pragma unroll
    for (int m = 0; m < 4; ++m) {
      int r = wr * 64 + m * 16 + l15;
      int sl = l4 ^ ((r >> 1) & 3);
      af[m] = *(const s16x8*)&lds[buf][0][r * 64 + (sl << 4)];
    }
    #pragma unroll
    for (int n = 0; n < 4; ++n) {
      int r = wc * 64 + n * 16 + l15;
      int sl = l4 ^ ((r >> 1) & 3);
      bfr[n] = *(const s16x8*)&lds[buf][1][r * 64 + (sl << 4)];
    }
    #pragma unroll
    for (int m = 0; m < 4; ++m)
      #pragma unroll
      for (int n = 0; n < 4; ++n)
        acc[m][n] = __builtin_amdgcn_mfma_f32_16x16x32_bf16(af[m], bfr[n], acc[m][n], 0, 0, 0);
    buf ^= 1;
  }

  #pragma unroll
  for (int m = 0; m < 4; ++m) {
    #pragma unroll
    for (int n = 0; n < 4; ++n) {
      #pragma unroll
      for (int i = 0; i < 4; ++i) {
        int row = br * 128 + wr * 64 + m * 16 + l4 * 4 + i;
        int col = bc * 128 + wc * 64 + n * 16 + l15;
        float v = acc[m][n][i] + (ROW_BIAS ? bias[row] : bias[col]);
        if (BF16_OUT) ((u16t*)Cv)[(size_t)row * N + col] = f2bf(v);
        else          ((float*)Cv)[(size_t)row * N + col] = v;
      }
    }
  }
}

// ---------------------------------------------------------------------------
// Flash attention, m214-style: 8 waves x 32 q-rows, KV tiles of 64,
// 32x32x16 MFMA, swapped QK^T (S^T: q lane-local) AND swapped PV
// (O^T: q lane-local) -> softmax state is pure lane-scalar.
// P stays in registers via cvt_pk_bf16 + permlane32_swap.
// LDS: planar subtile layout, conflict-free b128 reads, linear gload_lds.
//   K planes: sStage[buf][c2*1024 + kj*16]  = K[kv+kj][d = c2*8..+7]
//   V planes: sStage[buf][8192 + k2*1024 + d*16] = V[kv + k2*8..+7][d] (from VpT)
// ---------------------------------------------------------------------------
#define PKBF(dst, a, b) \
  asm("v_cvt_pk_bf16_f32 %0, %1, %2" : "=v"(dst) : "v"(a), "v"(b))

#define MAKE_FRAG(S, B, FR) { \
    u32t w0, w1, w2, w3; \
    PKBF(w0, S[B + 0], S[B + 1]); PKBF(w1, S[B + 2], S[B + 3]); \
    PKBF(w2, S[B + 4], S[B + 5]); PKBF(w3, S[B + 6], S[B + 7]); \
    u32x2 r02 = __builtin_amdgcn_permlane32_swap(w0, w2, false, false); \
    u32x2 r13 = __builtin_amdgcn_permlane32_swap(w1, w3, false, false); \
    union { u32t u[4]; s16x8 v; } uu; \
    uu.u[0] = r02[0]; uu.u[1] = r13[0]; uu.u[2] = r02[1]; uu.u[3] = r13[1]; \
    FR = uu.v; }

__global__ __launch_bounds__(512, 2)
void attn_fused(const u16t* __restrict__ Qp, const u16t* __restrict__ Kp,
                const u16t* __restrict__ VpT, u16t* __restrict__ AO) {
  __shared__ unsigned char sStage[2][16384];

  const int tid = threadIdx.x;
  const int lane = tid & 63;
  const int w = tid >> 6;          // 0..7
  const int l31 = lane & 31;
  const int hi = lane >> 5;        // 0/1
  const int h = blockIdx.y;
  const int qrow = blockIdx.x * 256 + w * 32 + l31;

  // Q B-fragments: lane holds Q[q=l31][d = c*16 + hi*8 + j]
  s16x8 qf[4];
  {
    const u16t* qsrc = Qp + (size_t)qrow * DM + h * DK + hi * 8;
    #pragma unroll
    for (int c = 0; c < 4; ++c) qf[c] = *(const s16x8*)(qsrc + c * 16);
  }

  f32x16 acc0 = {}, acc1 = {};        // O^T: d-tiles 0,1; q = l31
  float mrow = -3.0e38f, lrow = 0.f;

  auto stage = [&](int buf, int kv) {
    // wave w stages K plane c2=w and V plane k2=w (64 lanes x 16B each)
    GLOAD_LDS16(Kp + (size_t)(kv + lane) * DM + h * DK + w * 8,
                &sStage[buf][w * 1024]);
    GLOAD_LDS16(VpT + (size_t)(h * DK + lane) * L_SEQ + kv + w * 8,
                &sStage[buf][8192 + w * 1024]);
  };

  stage(0, 0);
  int buf = 0;

  for (int kv = 0; kv < L_SEQ; kv += 64) {
    __syncthreads();                      // staged tile `buf` ready
    if (kv + 64 < L_SEQ) stage(buf ^ 1, kv + 64);
    const unsigned char* sb = sStage[buf];

    // ---- QK^T (swapped): st = S^T[kj][q], q = l31 ----
    f32x16 st0 = {}, st1 = {};
    #pragma unroll
    for (int c = 0; c < 4; ++c) {
      const unsigned char* kp = sb + (((c * 2 + hi) << 10));
      s16x8 kf0 = *(const s16x8*)(kp + (l31 << 4));
      s16x8 kf1 = *(const s16x8*)(kp + ((32 + l31) << 4));
      st0 = __builtin_amdgcn_mfma_f32_32x32x16_bf16(kf0, qf[c], st0, 0, 0, 0);
      st1 = __builtin_amdgcn_mfma_f32_32x32x16_bf16(kf1, qf[c], st1, 0, 0, 0);
    }

    // ---- online softmax, fully lane-local (row q = l31) ----
    float mxa = st0[0], mxb = st1[0];
    #pragma unroll
    for (int r = 1; r < 16; ++r) {
      mxa = fmaxf(mxa, st0[r]);
      mxb = fmaxf(mxb, st1[r]);
    }
    float mx = fmaxf(mxa, mxb);
    mx = fmaxf(mx, __shfl_xor(mx, 32));   // partner half holds other 32 kj

    float mnew = fmaxf(mrow, mx);
    if (!__all(mx <= mrow)) {             // defer-max: skip when no row grew
      float alpha = __expf((mrow - mnew) * 0.125f);
      lrow *= alpha;
      #pragma unroll
      for (int r = 0; r < 16; ++r) { acc0[r] *= alpha; acc1[r] *= alpha; }
      mrow = mnew;
    }
    const float m8 = mrow * 0.125f;

    float rsa = 0.f, rsb = 0.f;
    #pragma unroll
    for (int r = 0; r < 16; ++r) {
      float p0 = __expf(fmaf(st0[r], 0.125f, -m8));
      float p1 = __expf(fmaf(st1[r], 0.125f, -m8));
      st0[r] = p0; st1[r] = p1;
      rsa += p0; rsb += p1;
    }
    float rs = rsa + rsb;
    rs += __shfl_xor(rs, 32);
    lrow += rs;

    // ---- PV (swapped): O^T += V^T · P^T ----
    #pragma unroll
    for (int cc = 0; cc < 4; ++cc) {
      s16x8 pfr;
      if (cc == 0)      MAKE_FRAG(st0, 0, pfr)
      else if (cc == 1) MAKE_FRAG(st0, 8, pfr)
      else if (cc == 2) MAKE_FRAG(st1, 0, pfr)
      else              MAKE_FRAG(st1, 8, pfr)
      const unsigned char* vp = sb + 8192 + ((cc * 2 + hi) << 10);
      s16x8 vf0 = *(const s16x8*)(vp + (l31 << 4));
      s16x8 vf1 = *(const s16x8*)(vp + ((32 + l31) << 4));
      acc0 = __builtin_amdgcn_mfma_f32_32x32x16_bf16(vf0, pfr, acc0, 0, 0, 0);
      acc1 = __builtin_amdgcn_mfma_f32_32x32x16_bf16(vf1, pfr, acc1, 0, 0, 0);
    }
    buf ^= 1;
  }

  // ---- epilogue: O^T regs -> AO[q][h*64+d], q = l31 (lane-local divide) ----
  const float inv = 1.0f / lrow;
  u16t* orow = AO + (size_t)qrow * DM + h * DK;
  #pragma unroll
  for (int r = 0; r < 16; ++r) {
    int d = (r & 3) + 8 * (r >> 2) + 4 * hi;
    orow[d]      = f2bf(acc0[r] * inv);
    orow[32 + d] = f2bf(acc1[r] * inv);
  }
}

// ---------------------------------------------------------------------------
extern "C" void kernel_launch(void* const* d_in, const int* in_sizes, int n_in,
                              void* d_out, int out_size, void* d_ws, size_t ws_size,
                              hipStream_t stream) {
  const float* query = (const float*)d_in[0];
  const float* key_  = (const float*)d_in[1];
  const float* value = (const float*)d_in[2];
  const float* Wq = (const float*)d_in[3];
  const float* Wk = (const float*)d_in[4];
  const float* Wv = (const float*)d_in[5];
  const float* Wo = (const float*)d_in[6];
  const float* bq = (const float*)d_in[7];
  const float* bk = (const float*)d_in[8];
  const float* bv = (const float*)d_in[9];
  const float* bo = (const float*)d_in[10];

  char* ws = (char*)d_ws;
  const size_t MB = 1u << 20;
  u16t* qb  = (u16t*)(ws + 0 * MB);
  u16t* kb  = (u16t*)(ws + 8 * MB);
  u16t* vb  = (u16t*)(ws + 16 * MB);
  u16t* wqb = (u16t*)(ws + 24 * MB);
  u16t* wkb = (u16t*)(ws + 26 * MB);
  u16t* wvb = (u16t*)(ws + 28 * MB);
  u16t* wob = (u16t*)(ws + 30 * MB);
  u16t* Qp  = (u16t*)(ws + 32 * MB);
  u16t* Kp  = (u16t*)(ws + 40 * MB);
  u16t* VpT = (u16t*)(ws + 48 * MB);  // [1024][4096]
  u16t* AO  = (u16t*)(ws + 56 * MB);

  const int nQKV = L_SEQ * DM;
  const int nW = DM * DM;
  dim3 blk(256);

  cvt_f32_bf16<<<dim3(nQKV / 2048), blk, 0, stream>>>(query, qb, nQKV);
  cvt_f32_bf16<<<dim3(nQKV / 2048), blk, 0, stream>>>(key_,  kb, nQKV);
  cvt_f32_bf16<<<dim3(nQKV / 2048), blk, 0, stream>>>(value, vb, nQKV);
  cvt_f32_bf16<<<dim3(nW / 2048), blk, 0, stream>>>(Wq, wqb, nW);
  cvt_f32_bf16<<<dim3(nW / 2048), blk, 0, stream>>>(Wk, wkb, nW);
  cvt_f32_bf16<<<dim3(nW / 2048), blk, 0, stream>>>(Wv, wvb, nW);
  cvt_f32_bf16<<<dim3(nW / 2048), blk, 0, stream>>>(Wo, wob, nW);

  gemm_bt<true, false><<<dim3(DM / 128, L_SEQ / 128), blk, 0, stream>>>(
      qb, wqb, bq, Qp, L_SEQ, DM, DM);
  gemm_bt<true, false><<<dim3(DM / 128, L_SEQ / 128), blk, 0, stream>>>(
      kb, wkb, bk, Kp, L_SEQ, DM, DM);
  gemm_bt<true, true><<<dim3(L_SEQ / 128, DM / 128), blk, 0, stream>>>(
      wvb, vb, bv, VpT, DM, L_SEQ, DM);

  attn_fused<<<dim3(L_SEQ / 256, NH), dim3(512), 0, stream>>>(Qp, Kp, VpT, AO);

  gemm_bt<false, false><<<dim3(DM / 128, L_SEQ / 128), blk, 0, stream>>>(
      AO, wob, bo, d_out, L_SEQ, DM, DM);
}

// Round 3
// 199.370 us; speedup vs baseline: 1.6172x; 1.0031x over previous
//
#include <hip/hip_runtime.h>

#define L_SEQ 4096
#define DM 1024
#define NH 16
#define DK 64

typedef short s16x8 __attribute__((ext_vector_type(8)));
typedef float f32x4 __attribute__((ext_vector_type(4)));
typedef float f32x16 __attribute__((ext_vector_type(16)));
typedef unsigned u32x2 __attribute__((ext_vector_type(2)));
typedef unsigned short u16t;
typedef unsigned int u32t;

typedef __attribute__((address_space(1))) unsigned int as1_u32;
typedef __attribute__((address_space(3))) unsigned int as3_u32;

#define GLOAD_LDS16(gsrc, ldst) \
  __builtin_amdgcn_global_load_lds((as1_u32*)(gsrc), (as3_u32*)(ldst), 16, 0, 0)

__device__ __forceinline__ u16t f2bf(float f) {
  union { float f; unsigned u; } v; v.f = f;
  unsigned u = v.u;
  u += 0x7fffu + ((u >> 16) & 1u);   // RNE
  return (u16t)(u >> 16);
}

__device__ __forceinline__ float fexp2(float x) {
  float r;
  asm("v_exp_f32 %0, %1" : "=v"(r) : "v"(x));
  return r;
}

// ---------------------------------------------------------------------------
// All 7 f32->bf16 conversions in ONE launch. Segments (8-elem groups):
// q,k,v: 3 x 524288 groups; Wq,Wk,Wv,Wo: 4 x 131072 groups. Total 2097152.
// ---------------------------------------------------------------------------
struct CvtArgs { const float* s[7]; u16t* d[7]; };

__global__ __launch_bounds__(256) void cvt_all(CvtArgs a) {
  int g = blockIdx.x * 256 + threadIdx.x;
  int seg, off;
  if (g < 1572864) { seg = g >> 19;               off = g & 524287; }
  else             { int t = g - 1572864; seg = 3 + (t >> 17); off = t & 131071; }
  const float* src = a.s[seg] + (size_t)off * 8;
  u16t* dst = a.d[seg] + (size_t)off * 8;
  float4 x = *(const float4*)(src);
  float4 y = *(const float4*)(src + 4);
  uint4 o;
  o.x = (u32t)f2bf(x.x) | ((u32t)f2bf(x.y) << 16);
  o.y = (u32t)f2bf(x.z) | ((u32t)f2bf(x.w) << 16);
  o.z = (u32t)f2bf(y.x) | ((u32t)f2bf(y.y) << 16);
  o.w = (u32t)f2bf(y.z) | ((u32t)f2bf(y.w) << 16);
  *(uint4*)dst = o;
}

// ---------------------------------------------------------------------------
// C[i][j] = (sum_k A[i][k] * B[j][k] + bias[j or i]) * oscale
// 128x64 tile (BM=128, BN=64), BK=32, 4 waves in 2x2. Grid = (N/64, M/128).
// LDS linear dest for global_load_lds, source pre-swizzled, reads swizzled.
// ---------------------------------------------------------------------------
template <bool BF16_OUT, bool ROW_BIAS>
__global__ __launch_bounds__(256)
void gemm_bt(const u16t* __restrict__ A, const u16t* __restrict__ B,
             const float* __restrict__ bias, void* __restrict__ Cv,
             int M, int N, int K, float oscale) {
  __shared__ unsigned char lds[2][12288];   // A: 0..8191, B: 8192..12287
  const int tid = threadIdx.x;
  const int lane = tid & 63;
  const int wv = tid >> 6;
  const int wr = wv >> 1, wc = wv & 1;
  const int l15 = lane & 15, l4 = lane >> 4;
  const int bc = blockIdx.x, br = blockIdx.y;

  const int r_st = tid >> 2;
  const int c_st = (tid & 3) ^ ((r_st >> 1) & 3);
  const u16t* a0 = A + (size_t)(br * 128 + r_st) * K + c_st * 8;
  const u16t* a1 = a0 + (size_t)64 * K;
  const u16t* b0 = B + (size_t)(bc * 64 + r_st) * K + c_st * 8;
  const int woff = wv * 1024;

  f32x4 acc[4][2] = {};

  auto stage = [&](int buf, int k0) {
    GLOAD_LDS16(a0 + k0, &lds[buf][woff]);
    GLOAD_LDS16(a1 + k0, &lds[buf][4096 + woff]);
    GLOAD_LDS16(b0 + k0, &lds[buf][8192 + woff]);
  };

  const int nt = K >> 5;
  stage(0, 0);
  int buf = 0;
  for (int t = 0; t < nt; ++t) {
    __syncthreads();
    if (t + 1 < nt) stage(buf ^ 1, (t + 1) * 32);
    s16x8 af[4], bfr[2];
    #pragma unroll
    for (int m = 0; m < 4; ++m) {
      int r = wr * 64 + m * 16 + l15;
      int sl = l4 ^ ((r >> 1) & 3);
      af[m] = *(const s16x8*)&lds[buf][r * 64 + (sl << 4)];
    }
    #pragma unroll
    for (int n = 0; n < 2; ++n) {
      int r = wc * 32 + n * 16 + l15;
      int sl = l4 ^ ((r >> 1) & 3);
      bfr[n] = *(const s16x8*)&lds[buf][8192 + r * 64 + (sl << 4)];
    }
    #pragma unroll
    for (int m = 0; m < 4; ++m)
      #pragma unroll
      for (int n = 0; n < 2; ++n)
        acc[m][n] = __builtin_amdgcn_mfma_f32_16x16x32_bf16(af[m], bfr[n], acc[m][n], 0, 0, 0);
    buf ^= 1;
  }

  #pragma unroll
  for (int m = 0; m < 4; ++m) {
    #pragma unroll
    for (int n = 0; n < 2; ++n) {
      #pragma unroll
      for (int i = 0; i < 4; ++i) {
        int row = br * 128 + wr * 64 + m * 16 + l4 * 4 + i;
        int col = bc * 64 + wc * 32 + n * 16 + l15;
        float v = (acc[m][n][i] + (ROW_BIAS ? bias[row] : bias[col])) * oscale;
        if (BF16_OUT) ((u16t*)Cv)[(size_t)row * N + col] = f2bf(v);
        else          ((float*)Cv)[(size_t)row * N + col] = v;
      }
    }
  }
}

// ---------------------------------------------------------------------------
// Flash attention: 4 waves x 32 q-rows (128 q/block), grid (32,16) = 512
// blocks = 2 independent blocks/CU. KV tiles of 64, 32x32x16 MFMA, swapped
// QK^T and PV (q lane-local both ways). Q pre-scaled by 0.125*log2e at
// projection, so softmax = exp2(st - m). P in-register via cvt_pk+permlane.
// ---------------------------------------------------------------------------
#define PKBF(dst, a, b) \
  asm("v_cvt_pk_bf16_f32 %0, %1, %2" : "=v"(dst) : "v"(a), "v"(b))

#define MAKE_FRAG(S, B, FR) { \
    u32t w0, w1, w2, w3; \
    PKBF(w0, S[B + 0], S[B + 1]); PKBF(w1, S[B + 2], S[B + 3]); \
    PKBF(w2, S[B + 4], S[B + 5]); PKBF(w3, S[B + 6], S[B + 7]); \
    u32x2 r02 = __builtin_amdgcn_permlane32_swap(w0, w2, false, false); \
    u32x2 r13 = __builtin_amdgcn_permlane32_swap(w1, w3, false, false); \
    union { u32t u[4]; s16x8 v; } uu; \
    uu.u[0] = r02[0]; uu.u[1] = r13[0]; uu.u[2] = r02[1]; uu.u[3] = r13[1]; \
    FR = uu.v; }

__global__ __launch_bounds__(256)
void attn_fused(const u16t* __restrict__ Qp, const u16t* __restrict__ Kp,
                const u16t* __restrict__ VpT, u16t* __restrict__ AO) {
  __shared__ unsigned char sStage[2][16384];

  const int tid = threadIdx.x;
  const int lane = tid & 63;
  const int w = tid >> 6;          // 0..3
  const int l31 = lane & 31;
  const int hi = lane >> 5;        // 0/1
  const int h = blockIdx.y;
  const int qrow = blockIdx.x * 128 + w * 32 + l31;

  // Q B-fragments: lane holds Q[q=l31][d = c*16 + hi*8 + j] (pre-scaled)
  s16x8 qf[4];
  {
    const u16t* qsrc = Qp + (size_t)qrow * DM + h * DK + hi * 8;
    #pragma unroll
    for (int c = 0; c < 4; ++c) qf[c] = *(const s16x8*)(qsrc + c * 16);
  }

  f32x16 acc0 = {}, acc1 = {};        // O^T: d-tiles 0,1; q = l31
  float mrow = -3.0e38f, lrow = 0.f;

  auto stage = [&](int buf, int kv) {
    // wave w stages K planes {w, w+4} and V planes {w, w+4}
    GLOAD_LDS16(Kp + (size_t)(kv + lane) * DM + h * DK + w * 8,
                &sStage[buf][w * 1024]);
    GLOAD_LDS16(Kp + (size_t)(kv + lane) * DM + h * DK + (w + 4) * 8,
                &sStage[buf][(w + 4) * 1024]);
    GLOAD_LDS16(VpT + (size_t)(h * DK + lane) * L_SEQ + kv + w * 8,
                &sStage[buf][8192 + w * 1024]);
    GLOAD_LDS16(VpT + (size_t)(h * DK + lane) * L_SEQ + kv + (w + 4) * 8,
                &sStage[buf][8192 + (w + 4) * 1024]);
  };

  stage(0, 0);
  int buf = 0;

  for (int kv = 0; kv < L_SEQ; kv += 64) {
    __syncthreads();                      // staged tile `buf` ready
    if (kv + 64 < L_SEQ) stage(buf ^ 1, kv + 64);
    const unsigned char* sb = sStage[buf];

    // ---- QK^T (swapped): st = S^T[kj][q], q = l31 ----
    f32x16 st0 = {}, st1 = {};
    #pragma unroll
    for (int c = 0; c < 4; ++c) {
      const unsigned char* kp = sb + (((c * 2 + hi) << 10));
      s16x8 kf0 = *(const s16x8*)(kp + (l31 << 4));
      s16x8 kf1 = *(const s16x8*)(kp + ((32 + l31) << 4));
      st0 = __builtin_amdgcn_mfma_f32_32x32x16_bf16(kf0, qf[c], st0, 0, 0, 0);
      st1 = __builtin_amdgcn_mfma_f32_32x32x16_bf16(kf1, qf[c], st1, 0, 0, 0);
    }

    // ---- online softmax, lane-local rows, tree reductions ----
    float m4[8];
    #pragma unroll
    for (int r = 0; r < 4; ++r) {
      m4[r]     = fmaxf(fmaxf(st0[4*r], st0[4*r+1]), fmaxf(st0[4*r+2], st0[4*r+3]));
      m4[4 + r] = fmaxf(fmaxf(st1[4*r], st1[4*r+1]), fmaxf(st1[4*r+2], st1[4*r+3]));
    }
    float mx = fmaxf(fmaxf(fmaxf(m4[0], m4[1]), fmaxf(m4[2], m4[3])),
                     fmaxf(fmaxf(m4[4], m4[5]), fmaxf(m4[6], m4[7])));
    mx = fmaxf(mx, __shfl_xor(mx, 32));   // partner half holds other 32 kj

    float mnew = fmaxf(mrow, mx);
    if (!__all(mx <= mrow)) {             // defer-max: skip when no row grew
      float alpha = fexp2(mrow - mnew);
      lrow *= alpha;
      #pragma unroll
      for (int r = 0; r < 16; ++r) { acc0[r] *= alpha; acc1[r] *= alpha; }
      mrow = mnew;
    }
    const float m2 = mrow;

    #pragma unroll
    for (int r = 0; r < 16; ++r) {
      st0[r] = fexp2(st0[r] - m2);
      st1[r] = fexp2(st1[r] - m2);
    }
    float s8[8];
    #pragma unroll
    for (int r = 0; r < 8; ++r)
      s8[r] = (st0[2*r] + st0[2*r+1]) + (st1[2*r] + st1[2*r+1]);
    float rs = ((s8[0] + s8[1]) + (s8[2] + s8[3])) +
               ((s8[4] + s8[5]) + (s8[6] + s8[7]));
    rs += __shfl_xor(rs, 32);
    lrow += rs;

    // ---- PV (swapped): O^T += V^T · P^T ----
    #pragma unroll
    for (int cc = 0; cc < 4; ++cc) {
      s16x8 pfr;
      if (cc == 0)      MAKE_FRAG(st0, 0, pfr)
      else if (cc == 1) MAKE_FRAG(st0, 8, pfr)
      else if (cc == 2) MAKE_FRAG(st1, 0, pfr)
      else              MAKE_FRAG(st1, 8, pfr)
      const unsigned char* vp = sb + 8192 + ((cc * 2 + hi) << 10);
      s16x8 vf0 = *(const s16x8*)(vp + (l31 << 4));
      s16x8 vf1 = *(const s16x8*)(vp + ((32 + l31) << 4));
      acc0 = __builtin_amdgcn_mfma_f32_32x32x16_bf16(vf0, pfr, acc0, 0, 0, 0);
      acc1 = __builtin_amdgcn_mfma_f32_32x32x16_bf16(vf1, pfr, acc1, 0, 0, 0);
    }
    buf ^= 1;
  }

  // ---- epilogue: O^T regs -> AO[q][h*64+d], q = l31 (lane-local divide) ----
  const float inv = 1.0f / lrow;
  u16t* orow = AO + (size_t)qrow * DM + h * DK;
  #pragma unroll
  for (int r = 0; r < 16; ++r) {
    int d = (r & 3) + 8 * (r >> 2) + 4 * hi;
    orow[d]      = f2bf(acc0[r] * inv);
    orow[32 + d] = f2bf(acc1[r] * inv);
  }
}

// ---------------------------------------------------------------------------
extern "C" void kernel_launch(void* const* d_in, const int* in_sizes, int n_in,
                              void* d_out, int out_size, void* d_ws, size_t ws_size,
                              hipStream_t stream) {
  const float* query = (const float*)d_in[0];
  const float* key_  = (const float*)d_in[1];
  const float* value = (const float*)d_in[2];
  const float* Wq = (const float*)d_in[3];
  const float* Wk = (const float*)d_in[4];
  const float* Wv = (const float*)d_in[5];
  const float* Wo = (const float*)d_in[6];
  const float* bq = (const float*)d_in[7];
  const float* bk = (const float*)d_in[8];
  const float* bv = (const float*)d_in[9];
  const float* bo = (const float*)d_in[10];

  char* ws = (char*)d_ws;
  const size_t MB = 1u << 20;
  u16t* qb  = (u16t*)(ws + 0 * MB);
  u16t* kb  = (u16t*)(ws + 8 * MB);
  u16t* vb  = (u16t*)(ws + 16 * MB);
  u16t* wqb = (u16t*)(ws + 24 * MB);
  u16t* wkb = (u16t*)(ws + 26 * MB);
  u16t* wvb = (u16t*)(ws + 28 * MB);
  u16t* wob = (u16t*)(ws + 30 * MB);
  u16t* Qp  = (u16t*)(ws + 32 * MB);
  u16t* Kp  = (u16t*)(ws + 40 * MB);
  u16t* VpT = (u16t*)(ws + 48 * MB);  // [1024][4096]
  u16t* AO  = (u16t*)(ws + 56 * MB);

  const float QSCALE = 0.125f * 1.4426950408889634f;  // fold 1/sqrt(dk) * log2e

  CvtArgs ca;
  ca.s[0] = query; ca.s[1] = key_; ca.s[2] = value;
  ca.s[3] = Wq; ca.s[4] = Wk; ca.s[5] = Wv; ca.s[6] = Wo;
  ca.d[0] = qb; ca.d[1] = kb; ca.d[2] = vb;
  ca.d[3] = wqb; ca.d[4] = wkb; ca.d[5] = wvb; ca.d[6] = wob;
  cvt_all<<<dim3(8192), dim3(256), 0, stream>>>(ca);

  // Q = (query @ Wq^T + bq) * QSCALE ; K plain
  gemm_bt<true, false><<<dim3(DM / 64, L_SEQ / 128), dim3(256), 0, stream>>>(
      qb, wqb, bq, Qp, L_SEQ, DM, DM, QSCALE);
  gemm_bt<true, false><<<dim3(DM / 64, L_SEQ / 128), dim3(256), 0, stream>>>(
      kb, wkb, bk, Kp, L_SEQ, DM, DM, 1.0f);
  // V^T directly: VpT[j][i] = Wv[j]·value[i] + bv[j]  (row-bias)
  gemm_bt<true, true><<<dim3(L_SEQ / 64, DM / 128), dim3(256), 0, stream>>>(
      wvb, vb, bv, VpT, DM, L_SEQ, DM, 1.0f);

  attn_fused<<<dim3(L_SEQ / 128, NH), dim3(256), 0, stream>>>(Qp, Kp, VpT, AO);

  // out = AO @ Wo^T + bo (f32 out)
  gemm_bt<false, false><<<dim3(DM / 64, L_SEQ / 128), dim3(256), 0, stream>>>(
      AO, wob, bo, d_out, L_SEQ, DM, DM, 1.0f);
}

// Round 4
// 163.389 us; speedup vs baseline: 1.9733x; 1.2202x over previous
//
#include <hip/hip_runtime.h>

#define L_SEQ 4096
#define DM 1024
#define NH 16
#define DK 64

typedef short s16x8 __attribute__((ext_vector_type(8)));
typedef float f32x4 __attribute__((ext_vector_type(4)));
typedef float f32x16 __attribute__((ext_vector_type(16)));
typedef unsigned u32x2 __attribute__((ext_vector_type(2)));
typedef unsigned short u16t;
typedef unsigned int u32t;

typedef __attribute__((address_space(1))) unsigned int as1_u32;
typedef __attribute__((address_space(3))) unsigned int as3_u32;

#define GLOAD_LDS16(gsrc, ldst) \
  __builtin_amdgcn_global_load_lds((as1_u32*)(gsrc), (as3_u32*)(ldst), 16, 0, 0)

__device__ __forceinline__ u16t f2bf(float f) {
  union { float f; unsigned u; } v; v.f = f;
  unsigned u = v.u;
  u += 0x7fffu + ((u >> 16) & 1u);   // RNE
  return (u16t)(u >> 16);
}

__device__ __forceinline__ float fexp2(float x) {
  float r;
  asm("v_exp_f32 %0, %1" : "=v"(r) : "v"(x));
  return r;
}

__device__ __forceinline__ float max3f(float a, float b, float c) {
  return fmaxf(fmaxf(a, b), c);   // fuses to v_max3_f32
}

// ---------------------------------------------------------------------------
// All 7 f32->bf16 conversions in ONE launch.
// ---------------------------------------------------------------------------
struct CvtArgs { const float* s[7]; u16t* d[7]; };

__global__ __launch_bounds__(256) void cvt_all(CvtArgs a) {
  int g = blockIdx.x * 256 + threadIdx.x;
  int seg, off;
  if (g < 1572864) { seg = g >> 19;               off = g & 524287; }
  else             { int t = g - 1572864; seg = 3 + (t >> 17); off = t & 131071; }
  const float* src = a.s[seg] + (size_t)off * 8;
  u16t* dst = a.d[seg] + (size_t)off * 8;
  float4 x = *(const float4*)(src);
  float4 y = *(const float4*)(src + 4);
  uint4 o;
  o.x = (u32t)f2bf(x.x) | ((u32t)f2bf(x.y) << 16);
  o.y = (u32t)f2bf(x.z) | ((u32t)f2bf(x.w) << 16);
  o.z = (u32t)f2bf(y.x) | ((u32t)f2bf(y.y) << 16);
  o.w = (u32t)f2bf(y.z) | ((u32t)f2bf(y.w) << 16);
  *(uint4*)dst = o;
}

// ---------------------------------------------------------------------------
// Batched QKV projection: one launch, 768 blocks (3 blocks/CU).
// z=0: Qp = (qb @ Wq^T + bq)*QSCALE   [4096x1024]
// z=1: Kp =  kb @ Wk^T + bk           [4096x1024]
// z=2: VpT = Wv @ value^T + bv(row)   [1024x4096]
// 128x128 tile, BK=32, 4 waves 2x2. K=1024 for all.
// ---------------------------------------------------------------------------
struct QkvArgs {
  const u16t* A[3]; const u16t* Bm[3]; const float* bias[3]; u16t* C[3];
  float scale0;
};

__global__ __launch_bounds__(256)
void gemm_qkv(QkvArgs ga) {
  __shared__ unsigned char lds[2][2][8192];
  const int bid = blockIdx.x;
  const int z = bid >> 8;
  const int b = bid & 255;
  const int bc = (z == 2) ? (b & 31) : (b & 7);
  const int br = (z == 2) ? (b >> 5) : (b >> 3);
  const int N  = (z == 2) ? L_SEQ : DM;
  const float osc = (z == 0) ? ga.scale0 : 1.0f;
  const bool rowb = (z == 2);
  const u16t* A = ga.A[z];
  const u16t* Bm = ga.Bm[z];
  const float* bias = ga.bias[z];
  u16t* C = ga.C[z];
  const int K = DM;

  const int tid = threadIdx.x;
  const int lane = tid & 63;
  const int wv = tid >> 6;
  const int wr = wv >> 1, wc = wv & 1;
  const int l15 = lane & 15, l4 = lane >> 4;

  const int r_st = tid >> 2;
  const int c_st = (tid & 3) ^ ((r_st >> 1) & 3);
  const u16t* a0 = A + (size_t)(br * 128 + r_st) * K + c_st * 8;
  const u16t* a1 = a0 + (size_t)64 * K;
  const u16t* b0 = Bm + (size_t)(bc * 128 + r_st) * K + c_st * 8;
  const u16t* b1 = b0 + (size_t)64 * K;
  const int woff = wv * 1024;

  f32x4 acc[4][4] = {};

  auto stage = [&](int buf, int k0) {
    GLOAD_LDS16(a0 + k0, &lds[buf][0][woff]);
    GLOAD_LDS16(a1 + k0, &lds[buf][0][4096 + woff]);
    GLOAD_LDS16(b0 + k0, &lds[buf][1][woff]);
    GLOAD_LDS16(b1 + k0, &lds[buf][1][4096 + woff]);
  };

  const int nt = K >> 5;
  stage(0, 0);
  int buf = 0;
  for (int t = 0; t < nt; ++t) {
    __syncthreads();
    if (t + 1 < nt) stage(buf ^ 1, (t + 1) * 32);
    s16x8 af[4], bfr[4];
    #pragma unroll
    for (int m = 0; m < 4; ++m) {
      int r = wr * 64 + m * 16 + l15;
      int sl = l4 ^ ((r >> 1) & 3);
      af[m] = *(const s16x8*)&lds[buf][0][r * 64 + (sl << 4)];
    }
    #pragma unroll
    for (int n = 0; n < 4; ++n) {
      int r = wc * 64 + n * 16 + l15;
      int sl = l4 ^ ((r >> 1) & 3);
      bfr[n] = *(const s16x8*)&lds[buf][1][r * 64 + (sl << 4)];
    }
    #pragma unroll
    for (int m = 0; m < 4; ++m)
      #pragma unroll
      for (int n = 0; n < 4; ++n)
        acc[m][n] = __builtin_amdgcn_mfma_f32_16x16x32_bf16(af[m], bfr[n], acc[m][n], 0, 0, 0);
    buf ^= 1;
  }

  #pragma unroll
  for (int m = 0; m < 4; ++m) {
    #pragma unroll
    for (int n = 0; n < 4; ++n) {
      #pragma unroll
      for (int i = 0; i < 4; ++i) {
        int row = br * 128 + wr * 64 + m * 16 + l4 * 4 + i;
        int col = bc * 128 + wc * 64 + n * 16 + l15;
        float v = (acc[m][n][i] + (rowb ? bias[row] : bias[col])) * osc;
        C[(size_t)row * N + col] = f2bf(v);
      }
    }
  }
}

// ---------------------------------------------------------------------------
// O projection: C[i][j] = sum_k A[i][k]*B[j][k] + bias[j], f32 out.
// 128x64 tile, grid (N/64, M/128) = 512 blocks.
// ---------------------------------------------------------------------------
__global__ __launch_bounds__(256)
void gemm_out(const u16t* __restrict__ A, const u16t* __restrict__ B,
              const float* __restrict__ bias, float* __restrict__ C,
              int M, int N, int K) {
  __shared__ unsigned char lds[2][12288];
  const int tid = threadIdx.x;
  const int lane = tid & 63;
  const int wv = tid >> 6;
  const int wr = wv >> 1, wc = wv & 1;
  const int l15 = lane & 15, l4 = lane >> 4;
  const int bc = blockIdx.x, br = blockIdx.y;

  const int r_st = tid >> 2;
  const int c_st = (tid & 3) ^ ((r_st >> 1) & 3);
  const u16t* a0 = A + (size_t)(br * 128 + r_st) * K + c_st * 8;
  const u16t* a1 = a0 + (size_t)64 * K;
  const u16t* b0 = B + (size_t)(bc * 64 + r_st) * K + c_st * 8;
  const int woff = wv * 1024;

  f32x4 acc[4][2] = {};

  auto stage = [&](int buf, int k0) {
    GLOAD_LDS16(a0 + k0, &lds[buf][woff]);
    GLOAD_LDS16(a1 + k0, &lds[buf][4096 + woff]);
    GLOAD_LDS16(b0 + k0, &lds[buf][8192 + woff]);
  };

  const int nt = K >> 5;
  stage(0, 0);
  int buf = 0;
  for (int t = 0; t < nt; ++t) {
    __syncthreads();
    if (t + 1 < nt) stage(buf ^ 1, (t + 1) * 32);
    s16x8 af[4], bfr[2];
    #pragma unroll
    for (int m = 0; m < 4; ++m) {
      int r = wr * 64 + m * 16 + l15;
      int sl = l4 ^ ((r >> 1) & 3);
      af[m] = *(const s16x8*)&lds[buf][r * 64 + (sl << 4)];
    }
    #pragma unroll
    for (int n = 0; n < 2; ++n) {
      int r = wc * 32 + n * 16 + l15;
      int sl = l4 ^ ((r >> 1) & 3);
      bfr[n] = *(const s16x8*)&lds[buf][8192 + r * 64 + (sl << 4)];
    }
    #pragma unroll
    for (int m = 0; m < 4; ++m)
      #pragma unroll
      for (int n = 0; n < 2; ++n)
        acc[m][n] = __builtin_amdgcn_mfma_f32_16x16x32_bf16(af[m], bfr[n], acc[m][n], 0, 0, 0);
    buf ^= 1;
  }

  #pragma unroll
  for (int m = 0; m < 4; ++m) {
    #pragma unroll
    for (int n = 0; n < 2; ++n) {
      #pragma unroll
      for (int i = 0; i < 4; ++i) {
        int row = br * 128 + wr * 64 + m * 16 + l4 * 4 + i;
        int col = bc * 64 + wc * 32 + n * 16 + l15;
        C[(size_t)row * N + col] = acc[m][n][i] + bias[col];
      }
    }
  }
}

// ---------------------------------------------------------------------------
// Flash attention: 8 waves x 32 q-rows (256 q/block), grid (16,16)=256.
// 32x32x16 MFMA, swapped QK^T and PV (q lane-local both ways). Q pre-scaled
// by 0.125*log2e -> softmax = exp2(st - m). P in-register (cvt_pk+permlane).
// 3-buffer counted-vmcnt pipeline: steady-state s_waitcnt vmcnt(2) keeps
// next tile's global_load_lds in flight across the barrier (T3/T4).
// ---------------------------------------------------------------------------
#define PKBF(dst, a, b) \
  asm("v_cvt_pk_bf16_f32 %0, %1, %2" : "=v"(dst) : "v"(a), "v"(b))

#define MAKE_FRAG(S, B, FR) { \
    u32t w0, w1, w2, w3; \
    PKBF(w0, S[B + 0], S[B + 1]); PKBF(w1, S[B + 2], S[B + 3]); \
    PKBF(w2, S[B + 4], S[B + 5]); PKBF(w3, S[B + 6], S[B + 7]); \
    u32x2 r02 = __builtin_amdgcn_permlane32_swap(w0, w2, false, false); \
    u32x2 r13 = __builtin_amdgcn_permlane32_swap(w1, w3, false, false); \
    union { u32t u[4]; s16x8 v; } uu; \
    uu.u[0] = r02[0]; uu.u[1] = r13[0]; uu.u[2] = r02[1]; uu.u[3] = r13[1]; \
    FR = uu.v; }

__global__ __launch_bounds__(512, 2)
void attn_fused(const u16t* __restrict__ Qp, const u16t* __restrict__ Kp,
                const u16t* __restrict__ VpT, u16t* __restrict__ AO) {
  __shared__ unsigned char sStage[3][16384];

  const int tid = threadIdx.x;
  const int lane = tid & 63;
  const int w = tid >> 6;          // 0..7
  const int l31 = lane & 31;
  const int hi = lane >> 5;        // 0/1
  const int h = blockIdx.y;
  const int qrow = blockIdx.x * 256 + w * 32 + l31;

  // Q B-fragments: lane holds Q[q=l31][d = c*16 + hi*8 + j] (pre-scaled)
  s16x8 qf[4];
  {
    const u16t* qsrc = Qp + (size_t)qrow * DM + h * DK + hi * 8;
    #pragma unroll
    for (int c = 0; c < 4; ++c) qf[c] = *(const s16x8*)(qsrc + c * 16);
  }

  f32x16 acc0 = {}, acc1 = {};        // O^T: d-tiles 0,1; q = l31
  float mrow = -3.0e38f, lrow = 0.f;

  auto stage = [&](int buf, int kv) {
    // wave w stages K plane c2=w and V plane k2=w (64 lanes x 16B each)
    GLOAD_LDS16(Kp + (size_t)(kv + lane) * DM + h * DK + w * 8,
                &sStage[buf][w * 1024]);
    GLOAD_LDS16(VpT + (size_t)(h * DK + lane) * L_SEQ + kv + w * 8,
                &sStage[buf][8192 + w * 1024]);
  };

  auto compute = [&](const unsigned char* sb) {
    // ---- QK^T (swapped): st = S^T[kj][q], q = l31 ----
    f32x16 st0 = {}, st1 = {};
    __builtin_amdgcn_s_setprio(1);
    #pragma unroll
    for (int c = 0; c < 4; ++c) {
      const unsigned char* kp = sb + (((c * 2 + hi) << 10));
      s16x8 kf0 = *(const s16x8*)(kp + (l31 << 4));
      s16x8 kf1 = *(const s16x8*)(kp + ((32 + l31) << 4));
      st0 = __builtin_amdgcn_mfma_f32_32x32x16_bf16(kf0, qf[c], st0, 0, 0, 0);
      st1 = __builtin_amdgcn_mfma_f32_32x32x16_bf16(kf1, qf[c], st1, 0, 0, 0);
    }
    __builtin_amdgcn_s_setprio(0);

    // ---- online softmax, lane-local rows, max3 trees ----
    float v0 = max3f(st0[0], st0[1], st0[2]);
    float v1 = max3f(st0[3], st0[4], st0[5]);
    float v2 = max3f(st0[6], st0[7], st0[8]);
    float v3 = max3f(st0[9], st0[10], st0[11]);
    float v4 = max3f(st0[12], st0[13], st0[14]);
    float v5 = max3f(st1[0], st1[1], st1[2]);
    float v6 = max3f(st1[3], st1[4], st1[5]);
    float v7 = max3f(st1[6], st1[7], st1[8]);
    float v8 = max3f(st1[9], st1[10], st1[11]);
    float v9 = max3f(st1[12], st1[13], st1[14]);
    float va = fmaxf(st0[15], st1[15]);
    float mx = max3f(max3f(v0, v1, v2), max3f(v3, v4, v5),
                     max3f(max3f(v6, v7, v8), v9, va));
    mx = fmaxf(mx, __shfl_xor(mx, 32));   // partner half holds other 32 kj

    float mnew = fmaxf(mrow, mx);
    if (!__all(mx <= mrow)) {             // defer-max: skip when no row grew
      float alpha = fexp2(mrow - mnew);
      lrow *= alpha;
      #pragma unroll
      for (int r = 0; r < 16; ++r) { acc0[r] *= alpha; acc1[r] *= alpha; }
      mrow = mnew;
    }
    const float m2 = mrow;

    #pragma unroll
    for (int r = 0; r < 16; ++r) {
      st0[r] = fexp2(st0[r] - m2);
      st1[r] = fexp2(st1[r] - m2);
    }
    float s8[8];
    #pragma unroll
    for (int r = 0; r < 8; ++r)
      s8[r] = (st0[2*r] + st0[2*r+1]) + (st1[2*r] + st1[2*r+1]);
    float rs = ((s8[0] + s8[1]) + (s8[2] + s8[3])) +
               ((s8[4] + s8[5]) + (s8[6] + s8[7]));
    rs += __shfl_xor(rs, 32);
    lrow += rs;

    // ---- PV (swapped): O^T += V^T · P^T ----
    __builtin_amdgcn_s_setprio(1);
    #pragma unroll
    for (int cc = 0; cc < 4; ++cc) {
      s16x8 pfr;
      if (cc == 0)      MAKE_FRAG(st0, 0, pfr)
      else if (cc == 1) MAKE_FRAG(st0, 8, pfr)
      else if (cc == 2) MAKE_FRAG(st1, 0, pfr)
      else              MAKE_FRAG(st1, 8, pfr)
      const unsigned char* vp = sb + 8192 + ((cc * 2 + hi) << 10);
      s16x8 vf0 = *(const s16x8*)(vp + (l31 << 4));
      s16x8 vf1 = *(const s16x8*)(vp + ((32 + l31) << 4));
      acc0 = __builtin_amdgcn_mfma_f32_32x32x16_bf16(vf0, pfr, acc0, 0, 0, 0);
      acc1 = __builtin_amdgcn_mfma_f32_32x32x16_bf16(vf1, pfr, acc1, 0, 0, 0);
    }
    __builtin_amdgcn_s_setprio(0);
  };

  stage(0, 0);
  stage(1, 64);
  int cur = 0, nstage = 2;
  // steady state: own outstanding loads = tile t (<=2) + tile t+1 (2);
  // vmcnt(2) => tile t's LDS writes landed; barrier => all waves' landed.
  for (int t = 0; t < 63; ++t) {
    asm volatile("s_waitcnt vmcnt(2)" ::: "memory");
    __builtin_amdgcn_s_barrier();
    __builtin_amdgcn_sched_barrier(0);
    if (t < 62) {
      stage(nstage, (t + 2) * 64);
      nstage = (nstage == 2) ? 0 : nstage + 1;
    }
    compute(sStage[cur]);
    cur = (cur == 2) ? 0 : cur + 1;
  }
  asm volatile("s_waitcnt vmcnt(0)" ::: "memory");
  __builtin_amdgcn_s_barrier();
  __builtin_amdgcn_sched_barrier(0);
  compute(sStage[cur]);

  // ---- epilogue: O^T regs -> AO[q][h*64+d], q = l31 (lane-local divide) ----
  const float inv = 1.0f / lrow;
  u16t* orow = AO + (size_t)qrow * DM + h * DK;
  #pragma unroll
  for (int r = 0; r < 16; ++r) {
    int d = (r & 3) + 8 * (r >> 2) + 4 * hi;
    orow[d]      = f2bf(acc0[r] * inv);
    orow[32 + d] = f2bf(acc1[r] * inv);
  }
}

// ---------------------------------------------------------------------------
extern "C" void kernel_launch(void* const* d_in, const int* in_sizes, int n_in,
                              void* d_out, int out_size, void* d_ws, size_t ws_size,
                              hipStream_t stream) {
  const float* query = (const float*)d_in[0];
  const float* key_  = (const float*)d_in[1];
  const float* value = (const float*)d_in[2];
  const float* Wq = (const float*)d_in[3];
  const float* Wk = (const float*)d_in[4];
  const float* Wv = (const float*)d_in[5];
  const float* Wo = (const float*)d_in[6];
  const float* bq = (const float*)d_in[7];
  const float* bk = (const float*)d_in[8];
  const float* bv = (const float*)d_in[9];
  const float* bo = (const float*)d_in[10];

  char* ws = (char*)d_ws;
  const size_t MB = 1u << 20;
  u16t* qb  = (u16t*)(ws + 0 * MB);
  u16t* kb  = (u16t*)(ws + 8 * MB);
  u16t* vb  = (u16t*)(ws + 16 * MB);
  u16t* wqb = (u16t*)(ws + 24 * MB);
  u16t* wkb = (u16t*)(ws + 26 * MB);
  u16t* wvb = (u16t*)(ws + 28 * MB);
  u16t* wob = (u16t*)(ws + 30 * MB);
  u16t* Qp  = (u16t*)(ws + 32 * MB);
  u16t* Kp  = (u16t*)(ws + 40 * MB);
  u16t* VpT = (u16t*)(ws + 48 * MB);  // [1024][4096]
  u16t* AO  = (u16t*)(ws + 56 * MB);

  const float QSCALE = 0.125f * 1.4426950408889634f;  // 1/sqrt(dk) * log2e

  CvtArgs ca;
  ca.s[0] = query; ca.s[1] = key_; ca.s[2] = value;
  ca.s[3] = Wq; ca.s[4] = Wk; ca.s[5] = Wv; ca.s[6] = Wo;
  ca.d[0] = qb; ca.d[1] = kb; ca.d[2] = vb;
  ca.d[3] = wqb; ca.d[4] = wkb; ca.d[5] = wvb; ca.d[6] = wob;
  cvt_all<<<dim3(8192), dim3(256), 0, stream>>>(ca);

  QkvArgs ga;
  ga.A[0] = qb;  ga.Bm[0] = wqb; ga.bias[0] = bq; ga.C[0] = Qp;
  ga.A[1] = kb;  ga.Bm[1] = wkb; ga.bias[1] = bk; ga.C[1] = Kp;
  ga.A[2] = wvb; ga.Bm[2] = vb;  ga.bias[2] = bv; ga.C[2] = VpT;
  ga.scale0 = QSCALE;
  gemm_qkv<<<dim3(768), dim3(256), 0, stream>>>(ga);

  attn_fused<<<dim3(L_SEQ / 256, NH), dim3(512), 0, stream>>>(Qp, Kp, VpT, AO);

  gemm_out<<<dim3(DM / 64, L_SEQ / 128), dim3(256), 0, stream>>>(
      AO, wob, bo, (float*)d_out, L_SEQ, DM, DM);
}